// Round 12
// baseline (470.475 us; speedup 1.0000x reference)
//
#include <hip/hip_runtime.h>
#include <hip/hip_bf16.h>
#include <math.h>

// ---------- dims ----------
#define BATCH 17
#define T_EX 16
#define H0 383
#define W0 287
#define C1 64
#define H1 95
#define W1 71
#define H1P 47
#define W1P 35
#define C2 192
#define H2P 23
#define W2P 17
#define C3 384
#define C45 256
#define H5P 11
#define W5P 8
#define DD 256
#define MM 88
#define TM 1408

#define HP1 389
#define WP1 292

typedef unsigned short ushort_t;
typedef __attribute__((ext_vector_type(8))) short short8;
typedef __attribute__((ext_vector_type(4))) float f32x4;

__device__ __forceinline__ float lrelu(float v) { return v > 0.f ? v : 0.01f * v; }

__device__ __forceinline__ ushort_t f2bf(float f) {
    unsigned int u = __float_as_uint(f);
    unsigned int r = (u + 0x7fffu + ((u >> 16) & 1u)) >> 16;
    return (ushort_t)r;
}
__device__ __forceinline__ float b2f(ushort_t b) {
    return __uint_as_float(((unsigned int)b) << 16);
}
__device__ __forceinline__ short8 ld16(const ushort_t* p) { return *(const short8*)p; }
__device__ __forceinline__ short8 ld2x8(const ushort_t* p) {
    union { uint2 u[2]; short8 s; } uu;
    uu.u[0] = *(const uint2*)p;
    uu.u[1] = *(const uint2*)(p + 4);
    return uu.s;
}
// async global -> LDS, 16B per lane; LDS dest = wave-uniform base + lane*16
__device__ __forceinline__ void async_cp16(ushort_t* l, const ushort_t* g) {
    __builtin_amdgcn_global_load_lds(
        (const __attribute__((address_space(1))) void*)g,
        (__attribute__((address_space(3))) void*)l, 16, 0, 0);
}

// ---------- conv weight prep body (shared by merged kernels) ----------
__device__ __forceinline__ void wprep_dev(const float* __restrict__ w,
                                          ushort_t* __restrict__ out,
                                          int KH, int KWl, int KWr, int CINl, int CINr,
                                          int NKS, int OCr, int idx) {
    int c = idx & 255;
    int rest = idx >> 8;
    int ks = rest % NKS;
    int ocb = rest / NKS;
    int k8 = c >> 6, m = c & 63;
    int oc = ocb * 64 + m;
    int KWC = KWl * CINl;
    ushort_t* o = out + (size_t)idx * 8;
#pragma unroll
    for (int j = 0; j < 8; ++j) {
        int kg = ks * 32 + k8 * 8 + j;
        int ky = kg / KWC; int rem = kg - ky * KWC;
        int kx = rem / CINl; int ic = rem - kx * CINl;
        float v = 0.f;
        if (oc < OCr && ky < KH && kx < KWr && ic < CINr)
            v = w[(((size_t)oc * CINr + ic) * KH + ky) * KWr + kx];
        o[j] = f2bf(v);
    }
}

// ---------- merged: conv1 input prep (pad-zero fused) + conv1 weight prep ----------
__global__ void prep1_wp1_k(const float* __restrict__ search, const float* __restrict__ exemp,
                            ushort_t* __restrict__ out, const float* __restrict__ w1,
                            ushort_t* __restrict__ WT) {
    const int pb = (BATCH * HP1 * WP1 + 255) / 256;   // 7543
    if ((int)blockIdx.x >= pb) {
        int idx = (blockIdx.x - pb) * 256 + threadIdx.x;
        if (idx < 4608) wprep_dev(w1, WT, 11, 12, 11, 4, 3, 18, 64, idx);
        return;
    }
    int idx = blockIdx.x * 256 + threadIdx.x;
    if (idx >= BATCH * HP1 * WP1) return;
    int x = idx % WP1; int t = idx / WP1;
    int y = t % HP1; int b = t / HP1;
    ushort4 o = {0, 0, 0, 0};
    int ix = x - 2, iy = y - 2;
    if (ix >= 0 && ix < W0 && iy >= 0 && iy < H0) {
        const float* src = (b == 0) ? search : exemp + (size_t)(b - 1) * 3 * H0 * W0;
        const int hw = H0 * W0;
        o.x = f2bf(src[iy * W0 + ix]);
        o.y = f2bf(src[hw + iy * W0 + ix]);
        o.z = f2bf(src[2 * hw + iy * W0 + ix]);
    }
    *(ushort4*)&out[(size_t)idx * 4] = o;
}

// ---------- merged: pool1 (pad-zero fused) + conv2 weight prep ----------
__global__ void pool_wp_k(const ushort_t* __restrict__ in, ushort_t* __restrict__ out,
                          int C, int Hin, int Win, int Hout, int Wout,
                          int OHp, int OWp, int OPAD,
                          const float* __restrict__ w, ushort_t* __restrict__ WT,
                          int KH, int KWl, int KWr, int CINl, int CINr,
                          int NKS, int nch, int OCr) {
    const int total = BATCH * C * OHp * OWp;
    const int pb = (total + 255) >> 8;
    int bx = blockIdx.x;
    if (bx >= pb) {
        int idx = (bx - pb) * 256 + threadIdx.x;
        if (idx < nch) wprep_dev(w, WT, KH, KWl, KWr, CINl, CINr, NKS, OCr, idx);
        return;
    }
    int idx = bx * 256 + threadIdx.x;
    if (idx >= total) return;
    int c = idx % C; int r = idx / C;
    int x = r % OWp; r /= OWp;
    int y = r % OHp; int b = r / OHp;
    int iy = y - OPAD, ix = x - OPAD;
    ushort_t v = 0;
    if (iy >= 0 && iy < Hout && ix >= 0 && ix < Wout) {
        const int rs = Win * C;
        const ushort_t* p = in + (((size_t)b * Hin + 2 * iy) * Win + 2 * ix) * C + c;
        float m = b2f(p[0]);
        m = fmaxf(m, b2f(p[C])); m = fmaxf(m, b2f(p[2 * C]));
        m = fmaxf(m, b2f(p[rs])); m = fmaxf(m, b2f(p[rs + C])); m = fmaxf(m, b2f(p[rs + 2 * C]));
        m = fmaxf(m, b2f(p[2 * rs])); m = fmaxf(m, b2f(p[2 * rs + C])); m = fmaxf(m, b2f(p[2 * rs + 2 * C]));
        v = f2bf(m);
    }
    out[idx] = v;
}

// ---------- mega-launch: pool2 (pads fused) + wprep3(WT) + wprep4(WT2)
// + wprep5(WT3) + gemm weight prep (WS1T/WS2T/WCDT).
// Buffer-disjointness audit: WT2/WT3/WS* live at R1+2800640.. (beyond
// c2out's 2684280 fl, which pool2 reads) -> race-free; all readers
// (conv4/conv5/gemm_pair/gemm_Y2) are stream-later. ----------
__global__ void pool_wp2big_k(const ushort_t* __restrict__ in, ushort_t* __restrict__ out,
                              const float* __restrict__ aw3, ushort_t* __restrict__ WT,
                              const float* __restrict__ aw4, ushort_t* __restrict__ WT2,
                              const float* __restrict__ aw5, ushort_t* __restrict__ WT3,
                              const float* __restrict__ ws1, const float* __restrict__ ws2,
                              const float* __restrict__ wcd, ushort_t* __restrict__ WS1T,
                              ushort_t* __restrict__ WS2T, ushort_t* __restrict__ WCDT) {
    int bx = blockIdx.x;
    if (bx < 6057) {   // pool2: c2out[47x35x192] -> p2out[25x19 pad1, 23x17x192]
        int idx = bx * 256 + threadIdx.x;
        const int total = BATCH * 192 * 25 * 19;
        if (idx >= total) return;
        int c = idx % 192; int r = idx / 192;
        int x = r % 19; r /= 19;
        int y = r % 25; int b = r / 25;
        int iy = y - 1, ix = x - 1;
        ushort_t v = 0;
        if (iy >= 0 && iy < H2P && ix >= 0 && ix < W2P) {
            const int rs = W1P * 192;
            const ushort_t* p = in + (((size_t)b * H1P + 2 * iy) * W1P + 2 * ix) * 192 + c;
            float m = b2f(p[0]);
            m = fmaxf(m, b2f(p[192])); m = fmaxf(m, b2f(p[384]));
            m = fmaxf(m, b2f(p[rs])); m = fmaxf(m, b2f(p[rs + 192])); m = fmaxf(m, b2f(p[rs + 384]));
            m = fmaxf(m, b2f(p[2 * rs])); m = fmaxf(m, b2f(p[2 * rs + 192])); m = fmaxf(m, b2f(p[2 * rs + 384]));
            v = f2bf(m);
        }
        out[idx] = v;
    } else if (bx < 6381) {        // wprep3 -> WT
        int idx = (bx - 6057) * 256 + threadIdx.x;
        if (idx < 82944) wprep_dev(aw3, WT, 3, 3, 3, 192, 192, 54, 384, idx);
    } else if (bx < 6813) {        // wprep4 -> WT2
        int idx = (bx - 6381) * 256 + threadIdx.x;
        if (idx < 110592) wprep_dev(aw4, WT2, 3, 3, 3, 384, 384, 108, 256, idx);
    } else if (bx < 7101) {        // wprep5 -> WT3
        int idx = (bx - 6813) * 256 + threadIdx.x;
        if (idx < 73728) wprep_dev(aw5, WT3, 3, 3, 3, 256, 256, 72, 256, idx);
    } else {                       // gemm weight prep -> WS1T/WS2T/WCDT
        int idx = (bx - 7101) * 256 + threadIdx.x;
        if (idx >= 57344) return;
        const float* src; ushort_t* dst; int NKS, mode = 0, sk = 0, base;
        if (idx < 16384)       { src = ws1; dst = WS1T; NKS = 8;  sk = 512; base = idx; }
        else if (idx < 32768)  { src = ws2; dst = WS2T; NKS = 16; sk = 256; base = idx - 16384; }
        else                   { src = wcd; dst = WCDT; NKS = 24; mode = 1; base = idx - 32768; }
        int c = base & 255;
        int rest = base >> 8;
        int ks = rest % NKS;
        int ocb = rest / NKS;
        int k8 = c >> 6, m = c & 63;
        int oc = ocb * 64 + m;
        ushort_t* o = dst + (size_t)base * 8;
#pragma unroll
        for (int j = 0; j < 8; ++j) {
            int kg = ks * 32 + k8 * 8 + j;
            float v;
            if (mode == 0) v = src[(size_t)oc + (size_t)kg * sk];
            else           v = src[(size_t)oc * 768 + (kg & 255) * 3 + (kg >> 8)];
            o[j] = f2bf(v);
        }
    }
}

// ====================================================================
// bf16 MFMA implicit-GEMM conv, v14 (41us conv2, r8/r11-verified) +
// optional ring-zero blocks (bx >= NBX, y==0): zero ONLY the 25x19 pad
// ring of the next conv's input (disjoint from interior cells written
// by this kernel's MFMA blocks -> race-free; ring + interior = full
// region -> bitwise-identical to the old whole-region zfill).
// ====================================================================
template <int STRIDE, bool A16>
__global__ __launch_bounds__(256) void conv_mfma14(
    const ushort_t* __restrict__ inp, const ushort_t* __restrict__ wt,
    const float* __restrict__ bias, ushort_t* __restrict__ out,
    int Hp, int Wp, int C, int Wout, int HW, int Ntot, int NKS2, int KWl,
    int OHp, int OWp, int OPAD, int COUT,
    int NBX, ushort_t* __restrict__ ringp, int ringChunks, int ringC) {
    const int tid = threadIdx.x;
    if ((int)blockIdx.x >= NBX) {
        if (blockIdx.y == 0 && ringp) {
            int idx = ((int)blockIdx.x - NBX) * 256 + tid;
            if (idx < ringChunks) {
                int pc = ringC >> 3;               // 16B chunks per pixel
                int b = idx / (84 * pc);
                int r = idx - b * 84 * pc;
                int rp = r / pc;
                int c8 = (r - rp * pc) * 8;
                int y, x;
                if (rp < 19)      { y = 0;  x = rp; }
                else if (rp < 38) { y = 24; x = rp - 19; }
                else if (rp < 61) { y = rp - 38 + 1; x = 0; }
                else              { y = rp - 61 + 1; x = 18; }
                short8 z = {0, 0, 0, 0, 0, 0, 0, 0};
                *(short8*)&ringp[(((size_t)b * 25 + y) * 19 + x) * ringC + c8] = z;
            }
        }
        return;
    }
    const int wv = tid >> 6, lane = tid & 63;
    const int quad = lane >> 4, l16 = lane & 15;
    const int wr = wv >> 1, wc = wv & 1;
    const int n_blk = blockIdx.x * 64;
    const int ocb = blockIdx.y;

    __shared__ ushort_t As[2][4096];
    __shared__ ushort_t Bs[2][4096];
    __shared__ int offs[432];

    const int KWC = KWl * C;
    for (int g = tid; g < NKS2 * 8; g += 256) {
        int kg = g * 8;
        int ky = kg / KWC; int rem = kg - ky * KWC;
        int kx = rem / C; int c8 = rem - kx * C;
        offs[g] = (ky * Wp + kx) * C + c8;
    }

    const size_t HWC = (size_t)Hp * Wp * C;
    const int g8 = lane & 7, po = lane >> 3;
    const ushort_t* bsrc0 = nullptr; const ushort_t* bsrc1 = nullptr;
    const ushort_t* lsrc = nullptr;
    int ws0 = 0, ws1 = 0;
    if constexpr (A16) {
        int np0 = n_blk + wv * 16 + po;      if (np0 >= Ntot) np0 = Ntot - 1;
        int np1 = n_blk + wv * 16 + 8 + po;  if (np1 >= Ntot) np1 = Ntot - 1;
        int b0 = np0 / HW, p0 = np0 - b0 * HW;
        int b1 = np1 / HW, p1 = np1 - b1 * HW;
        int oy0 = p0 / Wout, ox0 = p0 - oy0 * Wout;
        int oy1 = p1 / Wout, ox1 = p1 - oy1 * Wout;
        bsrc0 = inp + (size_t)b0 * HWC + (size_t)(oy0 * STRIDE * Wp + ox0 * STRIDE) * C;
        bsrc1 = inp + (size_t)b1 * HWC + (size_t)(oy1 * STRIDE * Wp + ox1 * STRIDE) * C;
        ws0 = g8 * 512 + (((wv * 16 + po) ^ g8) * 8);
        ws1 = g8 * 512 + (((wv * 16 + 8 + po) ^ g8) * 8);
    } else {
        int n0 = n_blk + lane; if (n0 >= Ntot) n0 = Ntot - 1;
        int b0 = n0 / HW, p0 = n0 - b0 * HW;
        int oy = p0 / Wout, ox = p0 - oy * Wout;
        lsrc = inp + (size_t)b0 * HWC + (size_t)(oy * STRIDE * Wp + ox * STRIDE) * C;
    }

    f32x4 acc[2][2];
#pragma unroll
    for (int am = 0; am < 2; ++am)
#pragma unroll
        for (int bn = 0; bn < 2; ++bn) acc[am][bn] = (f32x4){0.f, 0.f, 0.f, 0.f};

    const ushort_t* wblk = wt + (size_t)ocb * (size_t)NKS2 * 4096;

    __syncthreads();   // offs ready

    {
        const ushort_t* aS = wblk + tid * 8;
        async_cp16(&As[0][tid * 8], aS);
        async_cp16(&As[0][2048 + tid * 8], aS + 2048);
        if constexpr (A16) {
            *(short8*)&Bs[0][ws0] = ld16(bsrc0 + offs[g8]);
            *(short8*)&Bs[0][ws1] = ld16(bsrc1 + offs[g8]);
        } else {
            const int o0 = offs[wv], o1 = offs[4 + wv];
            *(short8*)&Bs[0][tid * 8] = ld2x8(lsrc + o0);
            *(short8*)&Bs[0][2048 + tid * 8] = ld2x8(lsrc + o1);
        }
    }
    __syncthreads();

    for (int ks2 = 0; ks2 < NKS2; ++ks2) {
        const int cur = ks2 & 1, nxt = cur ^ 1;
        const bool more = (ks2 + 1 < NKS2);
        short8 rb0, rb1;
        if (more) {
            const ushort_t* aS = wblk + (size_t)(ks2 + 1) * 4096 + tid * 8;
            async_cp16(&As[nxt][tid * 8], aS);
            async_cp16(&As[nxt][2048 + tid * 8], aS + 2048);
            if constexpr (A16) {
                rb0 = ld16(bsrc0 + offs[(ks2 + 1) * 8 + g8]);
                rb1 = ld16(bsrc1 + offs[(ks2 + 1) * 8 + g8]);
            } else {
                const int o0 = offs[(ks2 + 1) * 8 + wv], o1 = offs[(ks2 + 1) * 8 + 4 + wv];
                *(short8*)&Bs[nxt][tid * 8] = ld2x8(lsrc + o0);
                *(short8*)&Bs[nxt][2048 + tid * 8] = ld2x8(lsrc + o1);
            }
        }
#pragma unroll
        for (int h = 0; h < 2; ++h) {
            const short8 a0 = *(const short8*)&As[cur][h * 2048 + (quad * 64 + wr * 32 + l16) * 8];
            const short8 a1 = *(const short8*)&As[cur][h * 2048 + (quad * 64 + wr * 32 + 16 + l16) * 8];
            short8 b0, b1;
            if constexpr (A16) {
                b0 = *(const short8*)&Bs[cur][h * 2048 + quad * 512 + (((wc * 32 + l16) ^ (h * 4 + quad)) * 8)];
                b1 = *(const short8*)&Bs[cur][h * 2048 + quad * 512 + (((wc * 32 + 16 + l16) ^ (h * 4 + quad)) * 8)];
            } else {
                b0 = *(const short8*)&Bs[cur][h * 2048 + (quad * 64 + wc * 32 + l16) * 8];
                b1 = *(const short8*)&Bs[cur][h * 2048 + (quad * 64 + wc * 32 + 16 + l16) * 8];
            }
            acc[0][0] = __builtin_amdgcn_mfma_f32_16x16x32_bf16(a0, b0, acc[0][0], 0, 0, 0);
            acc[0][1] = __builtin_amdgcn_mfma_f32_16x16x32_bf16(a0, b1, acc[0][1], 0, 0, 0);
            acc[1][0] = __builtin_amdgcn_mfma_f32_16x16x32_bf16(a1, b0, acc[1][0], 0, 0, 0);
            acc[1][1] = __builtin_amdgcn_mfma_f32_16x16x32_bf16(a1, b1, acc[1][1], 0, 0, 0);
        }
        if constexpr (A16) {
            if (more) {
                *(short8*)&Bs[nxt][ws0] = rb0;
                *(short8*)&Bs[nxt][ws1] = rb1;
            }
        }
        __syncthreads();
    }

    const int oc0 = ocb * 64 + wr * 32 + quad * 4;
#pragma unroll
    for (int bn = 0; bn < 2; ++bn) {
        int n = n_blk + wc * 32 + bn * 16 + l16;
        if (n < Ntot) {
            int bb = n / HW; int pix = n - bb * HW;
            int y = pix / Wout, x = pix - y * Wout;
            size_t base = (((size_t)bb * OHp + y + OPAD) * OWp + x + OPAD) * COUT;
#pragma unroll
            for (int am = 0; am < 2; ++am) {
                const int oc = oc0 + am * 16;
                ushort4 o;
                o.x = f2bf(fmaxf(acc[am][bn][0] + bias[oc], 0.f));
                o.y = f2bf(fmaxf(acc[am][bn][1] + bias[oc + 1], 0.f));
                o.z = f2bf(fmaxf(acc[am][bn][2] + bias[oc + 2], 0.f));
                o.w = f2bf(fmaxf(acc[am][bn][3] + bias[oc + 3], 0.f));
                *(ushort4*)&out[base + oc] = o;
            }
        }
    }
}

// ====================================================================
// Generic bf16 MFMA GEMM body (device fn).
// ====================================================================
template <int MODE, bool HASBIAS, bool SC1>
__device__ __forceinline__ void gemm_dev(
    ushort_t (*Bs)[2048],
    const ushort_t* __restrict__ Bsrc, const ushort_t* __restrict__ wt,
    const float* __restrict__ bias, float* __restrict__ out,
    int RS, int N, int NKS, int sn, int sc, int bx, int by) {
    const int tid = threadIdx.x;
    const int wv = tid >> 6, lane = tid & 63;
    const int quad = lane >> 4, l16 = lane & 15;
    const int n_blk = bx * 64;
    const int ocb = by;

    int n_g = n_blk + lane;
    int n_gc = n_g < N ? n_g : N - 1;
    int row = (MODE == 1) ? (1 + (n_gc & 15)) * MM + (n_gc >> 4) : n_gc;
    const size_t base0 = (size_t)row * RS;

    f32x4 acc[4];
#pragma unroll
    for (int cn = 0; cn < 4; ++cn) acc[cn] = (f32x4){0.f, 0.f, 0.f, 0.f};

    const ushort_t* wblk = wt + (size_t)ocb * NKS * 2048;
    const int afrag = (quad * 64 + wv * 16 + l16) * 8;

    short8 a0 = ld16(wblk + afrag);
    *(short8*)&Bs[0][tid * 8] = ld16(Bsrc + base0 + wv * 8);
    __syncthreads();

    for (int ks = 0; ks < NKS; ++ks) {
        const int cur = ks & 1, nxt = cur ^ 1;
        short8 a1, bn;
        const bool more = (ks + 1 < NKS);
        if (more) {
            a1 = ld16(wblk + (ks + 1) * 2048 + afrag);
            bn = ld16(Bsrc + base0 + (ks + 1) * 32 + wv * 8);
        }
#pragma unroll
        for (int cn = 0; cn < 4; ++cn) {
            const short8 bfr = *(const short8*)&Bs[cur][(quad * 64 + cn * 16 + l16) * 8];
            acc[cn] = __builtin_amdgcn_mfma_f32_16x16x32_bf16(a0, bfr, acc[cn], 0, 0, 0);
        }
        if (more) *(short8*)&Bs[nxt][tid * 8] = bn;
        a0 = a1;
        __syncthreads();
    }

    const int oc0 = ocb * 64 + wv * 16 + quad * 4;
    float bb[4] = {0.f, 0.f, 0.f, 0.f};
    if (HASBIAS) { bb[0] = bias[oc0]; bb[1] = bias[oc0+1]; bb[2] = bias[oc0+2]; bb[3] = bias[oc0+3]; }
#pragma unroll
    for (int cn = 0; cn < 4; ++cn) {
        int n = n_blk + cn * 16 + l16;
        if (n < N) {
            if (SC1) {
                float4 o;
                o.x = acc[cn][0] + bb[0]; o.y = acc[cn][1] + bb[1];
                o.z = acc[cn][2] + bb[2]; o.w = acc[cn][3] + bb[3];
                *(float4*)&out[(size_t)n * sn + oc0] = o;
            } else {
#pragma unroll
                for (int reg = 0; reg < 4; ++reg)
                    out[(size_t)n * sn + (size_t)(oc0 + reg) * sc] = acc[cn][reg] + bb[reg];
            }
        }
    }
}

template <int MODE, bool HASBIAS, bool SC1>
__global__ __launch_bounds__(256) void gemm_mfma3_k(
    const ushort_t* __restrict__ Bsrc, const ushort_t* __restrict__ wt,
    const float* __restrict__ bias, float* __restrict__ out,
    int RS, int N, int NKS, int sn, int sc) {
    __shared__ ushort_t Bs[2][2048];
    gemm_dev<MODE, HASBIAS, SC1>(Bs, Bsrc, wt, bias, out, RS, N, NKS, sn, sc,
                                 blockIdx.x, blockIdx.y);
}

// merged launch: xc-gemm (2x4 blocks) + Y1-gemm (22x8 blocks); grid (24,8)
__global__ __launch_bounds__(256) void gemm_pair_k(
    const ushort_t* __restrict__ XfPad, const ushort_t* __restrict__ WCDT,
    const float* __restrict__ bcd, float* __restrict__ xc,
    const ushort_t* __restrict__ PB, const ushort_t* __restrict__ WS1T,
    float* __restrict__ Y1) {
    __shared__ ushort_t Bs[2][2048];
    if (blockIdx.x < 2) {
        if (blockIdx.y < 4)
            gemm_dev<0, true, false>(Bs, XfPad, WCDT, bcd, xc, 256, MM, 24, 1, MM,
                                     blockIdx.x, blockIdx.y);
    } else {
        gemm_dev<1, false, true>(Bs, PB, WS1T, nullptr, Y1, 256, TM, 8, 512, 1,
                                 blockIdx.x - 2, blockIdx.y);
    }
}

// ---------- pool5 ----------
__global__ void pool5_k(const ushort_t* __restrict__ in, float* __restrict__ P,
                        ushort_t* __restrict__ PB, ushort_t* __restrict__ XfPad) {
    int idx = blockIdx.x * 256 + threadIdx.x;
    if (idx >= BATCH * 256 * MM) return;
    int c = idx % 256; int r = idx / 256;
    int x = r % W5P; r /= W5P;
    int y = r % H5P; int b = r / H5P;
    const int rs = W2P * 256;
    const ushort_t* p = in + (((size_t)b * H2P + 2 * y) * W2P + 2 * x) * 256 + c;
    float m = b2f(p[0]);
    m = fmaxf(m, b2f(p[256])); m = fmaxf(m, b2f(p[512]));
    m = fmaxf(m, b2f(p[rs])); m = fmaxf(m, b2f(p[rs + 256])); m = fmaxf(m, b2f(p[rs + 512]));
    m = fmaxf(m, b2f(p[2 * rs])); m = fmaxf(m, b2f(p[2 * rs + 256])); m = fmaxf(m, b2f(p[2 * rs + 512]));
    int mm = y * W5P + x;
    size_t o = ((size_t)b * MM + mm) * 256 + c;
    P[o] = m;
    ushort_t mb = f2bf(m);
    PB[o] = mb;
    if (b == 0) XfPad[(size_t)(mm + 1) * 256 + c] = mb;
}

// ---------- merged: xhat (with in-block vmax) + sh1 (r8 config, 120x256) ----------
__global__ void xhat_sh1_k(const float* __restrict__ xc, const float* __restrict__ wt,
                           const float* __restrict__ bt, float* __restrict__ xhat,
                           const float* __restrict__ Y1, const float* __restrict__ bs1,
                           ushort_t* __restrict__ h1b) {
    if (blockIdx.x < 88) {
        __shared__ float lv[256];
        {
            int j = threadIdx.x;
            const float* xr = xc + (size_t)j * MM;
            float mx = xr[0];
            for (int k = 1; k < MM; ++k) mx = fmaxf(mx, xr[k]);
            lv[j] = mx;
        }
        __syncthreads();
        int idx = blockIdx.x * 256 + threadIdx.x;
        if (idx >= DD * MM) return;
        int k = idx % MM, o = idx / MM;
        float acc = bt[o];
        for (int i = 0; i < 256; ++i) acc = fmaf(lv[i], wt[(i * 256 + o) * MM + k], acc);
        xhat[idx] = acc;
    } else {
        int idx = (blockIdx.x - 88) * 256 + threadIdx.x;
        if (idx >= T_EX * 512) return;
        int c = idx & 511, t = idx >> 9;
        float s = 0.f;
        for (int m = 0; m < MM; ++m) s += Y1[(size_t)(m * T_EX + t) * 512 + c];
        float base = s + bs1[c];
        if (t == 0) {
            for (int m = 0; m < MM; ++m) {
                float val = base - Y1[(size_t)(m * T_EX) * 512 + c];
                h1b[(size_t)(m * T_EX) * 512 + c] = f2bf(lrelu(val));
            }
        } else {
            ushort_t v = f2bf(lrelu(base));
            for (int m = 0; m < MM; ++m)
                h1b[(size_t)(m * T_EX + t) * 512 + c] = v;
        }
    }
}

// ---------- fused sh2 + v1vx (r9/r11-verified bit-exact) ----------
__global__ void sh2v1_k(const float* __restrict__ Y2, const float* __restrict__ bs2,
                        const float* __restrict__ xhat,
                        float* __restrict__ V1, float* __restrict__ Vx) {
    int d = blockIdx.x;
    int tid = threadIdx.x;   // 128
    __shared__ float S2s[16];
    if (tid < 16) {
        float s = 0.f;
        for (int m = 0; m < MM; ++m) s += Y2[(size_t)(m * T_EX + tid) * 256 + d];
        S2s[tid] = s + bs2[d];
    }
    __syncthreads();
    for (int m = tid; m < MM; m += 128) {
        float y0 = Y2[(size_t)(m * T_EX) * 256 + d];
        float mx = -INFINITY;
        for (int t = 0; t < T_EX; ++t) {
            float val = (t == 0) ? lrelu(S2s[0] - y0) : lrelu(S2s[t]);
            mx = fmaxf(mx, val);
        }
        int idx = d * MM + m;
        V1[idx] = mx;
        Vx[idx] = mx + xhat[idx];
    }
}

// ---------- merged: lin88 (g & h) + t1 (r8 config, 308x256) ----------
__global__ void lin_t1_k(const float* __restrict__ Wgm, const float* __restrict__ bg,
                         const float* __restrict__ Whm, const float* __restrict__ bh,
                         const float* __restrict__ Vx, float* __restrict__ G,
                         float* __restrict__ Hh,
                         const float* __restrict__ V1, const float* __restrict__ wc1,
                         float* __restrict__ t1) {
    int bx = blockIdx.x;
    if (bx < 176) {
        int sel = bx >= 88;
        int idx = (bx - (sel ? 88 : 0)) * 256 + threadIdx.x;
        if (idx >= DD * MM) return;
        const float* W = sel ? Whm : Wgm;
        const float* bias = sel ? bh : bg;
        float* out = sel ? Hh : G;
        int m = idx % MM, o = idx / MM;
        const float* wr = W + o * 256;
        float acc = bias[o];
        for (int i = 0; i < 256; ++i) acc = fmaf(wr[i], Vx[i * MM + m], acc);
        out[idx] = acc;
    } else {
        int idx = (bx - 176) * 256 + threadIdx.x;
        if (idx >= MM * 384) return;
        int c = idx % 384, m = idx / 384;
        float acc = 0.f;
        for (int d = 0; d < 256; ++d) acc = fmaf(V1[d * MM + m], wc1[d * 384 + c], acc);
        t1[idx] = acc;
    }
}

// ---------- fused Smat row + softmax ----------
__global__ void smsm_k(const float* __restrict__ Hh, const float* __restrict__ G,
                       float* __restrict__ A2) {
    int j = blockIdx.x;
    int tid = threadIdx.x;   // 128
    __shared__ float row[96];
    __shared__ float red[128];
    for (int i = tid; i < MM; i += 128) {
        float acc = 0.f;
        for (int c = 0; c < 256; ++c) acc = fmaf(Hh[c * MM + j], G[c * MM + i], acc);
        row[i] = acc;
    }
    __syncthreads();
    float val = (tid < MM) ? row[tid] : -INFINITY;
    red[tid] = val; __syncthreads();
    for (int s = 64; s > 0; s >>= 1) {
        if (tid < s) red[tid] = fmaxf(red[tid], red[tid + s]);
        __syncthreads();
    }
    float mx = red[0]; __syncthreads();
    float e = (tid < MM) ? expf(val - mx) : 0.f;
    red[tid] = e; __syncthreads();
    for (int s = 64; s > 0; s >>= 1) {
        if (tid < s) red[tid] += red[tid + s];
        __syncthreads();
    }
    float inv = 1.f / red[0];
    if (tid < MM) A2[j * MM + tid] = e * inv;
}

// ---------- c1 (132x256); block 0 zeroes the v2f counter ----------
__global__ void c1_k(const float* __restrict__ A2, const float* __restrict__ t1,
                     const float* __restrict__ bc1, float* __restrict__ c1,
                     unsigned* __restrict__ cnt) {
    if (blockIdx.x == 0 && threadIdx.x == 0) *cnt = 0u;
    int idx = blockIdx.x * 256 + threadIdx.x;
    if (idx >= MM * 384) return;
    int c = idx % 384, j = idx / 384;
    float acc = bc1[c];
    for (int i = 0; i < MM; ++i) acc = fmaf(A2[j * MM + i], t1[i * 384 + c], acc);
    c1[idx] = lrelu(acc);
}

// ---------- t2 (88x256) ----------
__global__ void t2_k(const float* __restrict__ c1, const float* __restrict__ wc2,
                     float* __restrict__ t2) {
    int idx = blockIdx.x * 256 + threadIdx.x;
    if (idx >= MM * 256) return;
    int c = idx % 256, m = idx / 256;
    const float* cr = c1 + m * 384;
    float acc = 0.f;
    for (int d = 0; d < 384; ++d) acc = fmaf(cr[d], wc2[d * 256 + c], acc);
    t2[idx] = acc;
}

// ---------- fused v2 + final (r9/r11-verified deterministic last-block) ----------
__global__ __launch_bounds__(256) void v2f_k(const float* __restrict__ A2,
                                             const float* __restrict__ t2,
                                             const float* __restrict__ bc2,
                                             const float* __restrict__ Xf2,
                                             float* __restrict__ V2m,
                                             unsigned* __restrict__ cnt,
                                             float* __restrict__ out) {
    int j = blockIdx.x;   // 88
    int tid = threadIdx.x;
    __shared__ float a2row[88];
    if (tid < 88) a2row[tid] = A2[j * MM + tid];
    __syncthreads();
    {
        int c = tid;
        float acc = bc2[c];
        for (int i = 0; i < MM; ++i) acc = fmaf(a2row[i], t2[i * 256 + c], acc);
        V2m[(size_t)j * 256 + c] = lrelu(acc);
    }
    __threadfence();
    __syncthreads();
    __shared__ bool last;
    if (tid == 0) last = (atomicAdd(cnt, 1u) == 87u);
    __syncthreads();
    if (last) {
        __threadfence();
        __shared__ float red[256];
        float acc = 0.f;
        for (int idx = tid; idx < DD * MM; idx += 256)
            acc = fmaf(Xf2[idx], V2m[idx], acc);
        red[tid] = acc; __syncthreads();
        for (int s = 128; s > 0; s >>= 1) {
            if (tid < s) red[tid] += red[tid + s];
            __syncthreads();
        }
        if (tid == 0) out[0] = red[0];
    }
}

extern "C" void kernel_launch(void* const* d_in, const int* in_sizes, int n_in,
                              void* d_out, int out_size, void* d_ws, size_t ws_size,
                              hipStream_t stream) {
    const float* search = (const float*)d_in[0];
    const float* exemp  = (const float*)d_in[1];
    const float* aw1 = (const float*)d_in[2];  const float* ab1 = (const float*)d_in[3];
    const float* aw2 = (const float*)d_in[4];  const float* ab2 = (const float*)d_in[5];
    const float* aw3 = (const float*)d_in[6];  const float* ab3 = (const float*)d_in[7];
    const float* aw4 = (const float*)d_in[8];  const float* ab4 = (const float*)d_in[9];
    const float* aw5 = (const float*)d_in[10]; const float* ab5 = (const float*)d_in[11];
    const float* wcd = (const float*)d_in[12]; const float* bcd = (const float*)d_in[13];
    const float* wt  = (const float*)d_in[14]; const float* bt  = (const float*)d_in[15];
    const float* ws1 = (const float*)d_in[16]; const float* bs1 = (const float*)d_in[17];
    const float* ws2 = (const float*)d_in[18]; const float* bs2 = (const float*)d_in[19];
    const float* wg  = (const float*)d_in[20]; const float* bg  = (const float*)d_in[21];
    const float* wh  = (const float*)d_in[22]; const float* bh  = (const float*)d_in[23];
    const float* wc1 = (const float*)d_in[24]; const float* bc1 = (const float*)d_in[25];
    const float* wc2 = (const float*)d_in[26]; const float* bc2 = (const float*)d_in[27];

    float* ws = (float*)d_ws;
    float* R1 = ws;
    float* R2 = ws + 3870720;
    float* R3 = ws + 7544832;
    float* Wg = ws + 8628864;

    ushort_t* in1p  = (ushort_t*)R1;
    ushort_t* c1out = (ushort_t*)R2;
    ushort_t* p1out = (ushort_t*)R3;
    ushort_t* c2out = (ushort_t*)R1;
    ushort_t* p2out = (ushort_t*)R2;
    ushort_t* c3out = (ushort_t*)(R2 + 775200);
    ushort_t* c4out = (ushort_t*)R1;
    ushort_t* c5out = (ushort_t*)R3;
    ushort_t* WT    = (ushort_t*)Wg;                  // conv1/2/3 (sequential reuse)
    ushort_t* WT2   = (ushort_t*)(R1 + 2800640);      // conv4 (dead in1p territory)
    ushort_t* WT3   = (ushort_t*)(R1 + 3243008);      // conv5
    ushort_t* WS1T  = (ushort_t*)(R1 + 3537920);
    ushort_t* WS2T  = (ushort_t*)(R1 + 3603456);
    ushort_t* WCDT  = (ushort_t*)(R1 + 3668992);      // ends 3767296 < 3870720

    // ---- conv stack ----
    prep1_wp1_k<<<7543 + 18, 256, 0, stream>>>(search, exemp, in1p, aw1, WT);
    conv_mfma14<4, false><<<dim3(1792, 1), 256, 0, stream>>>(
        in1p, WT, ab1, c1out, HP1, WP1, 4, W1, H1 * W1, BATCH * H1 * W1, 9, 12, H1, W1, 0, 64,
        1792, nullptr, 0, 0);
    pool_wp_k<<<8454 + 150, 256, 0, stream>>>(
        c1out, p1out, 64, H1, W1, H1P, W1P, 51, 39, 2,
        aw2, WT, 5, 5, 5, 64, 64, 50, 38400, 192);
    conv_mfma14<1, true><<<dim3(437, 3), 256, 0, stream>>>(
        p1out, WT, ab2, c2out, 51, 39, 64, W1P, H1P * W1P, BATCH * H1P * W1P, 25, 5, H1P, W1P, 0, 192,
        437, nullptr, 0, 0);
    // mega-launch: pool2 + wprep3(WT) + wprep4(WT2) + wprep5(WT3) + gemm-wprep
    pool_wp2big_k<<<7325, 256, 0, stream>>>(
        c2out, p2out, aw3, WT, aw4, WT2, aw5, WT3, ws1, ws2, wcd, WS1T, WS2T, WCDT);
    // conv3 + c3out pad-ring zero (ring disjoint from interior writes)
    conv_mfma14<1, true><<<dim3(104 + 268, 6), 256, 0, stream>>>(
        p2out, WT, ab3, c3out, 25, 19, 192, W2P, H2P * W2P, BATCH * H2P * W2P, 27, 3, 25, 19, 1, 384,
        104, c3out, 68544, 384);
    // conv4 + c4out pad-ring zero
    conv_mfma14<1, true><<<dim3(104 + 179, 4), 256, 0, stream>>>(
        c3out, WT2, ab4, c4out, 25, 19, 384, W2P, H2P * W2P, BATCH * H2P * W2P, 54, 3, 25, 19, 1, 256,
        104, c4out, 45696, 256);
    conv_mfma14<1, true><<<dim3(104, 4), 256, 0, stream>>>(
        c4out, WT3, ab5, c5out, 25, 19, 256, W2P, H2P * W2P, BATCH * H2P * W2P, 36, 3, H2P, W2P, 0, 256,
        104, nullptr, 0, 0);

    // ---- tail region layout in R1 ----
    float*    P      = R1 + 2417664;
    ushort_t* PB     = (ushort_t*)(R1 + 2800640);
    ushort_t* XfPad  = (ushort_t*)(R1 + 2992128);
    float*    xc     = R1 + 3003648;

    pool5_k<<<1496, 256, 0, stream>>>(c5out, P, PB, XfPad);
    float* Xf2 = P;

    float* xhat = R1 + 1024;
    float* Y1   = R1 + 23552;
    ushort_t* h1b = (ushort_t*)(R1 + 752640);
    float* Y2   = R1 + 1473536;
    float* V1   = R1 + 2198528;
    float* Vx   = R1 + 2221056;
    float* G    = R1 + 2243584;
    float* Hh   = R1 + 2266112;
    float* A2   = R1 + 2296832;
    float* t1   = R1 + 2305024;
    float* c1   = R1 + 2338816;
    float* t2   = R1 + 2372608;
    float* V2m  = R1 + 2395136;
    unsigned* cnt = (unsigned*)(R1 + 512);   // scratch; zeroed by c1_k

    gemm_pair_k<<<dim3(24, 8), 256, 0, stream>>>(XfPad, WCDT, bcd, xc, PB, WS1T, Y1);
    xhat_sh1_k<<<120, 256, 0, stream>>>(xc, wt, bt, xhat, Y1, bs1, h1b);

    gemm_mfma3_k<0, false, true><<<dim3(22, 4), 256, 0, stream>>>(
        h1b, WS2T, nullptr, Y2, 512, TM, 16, 256, 1);
    sh2v1_k<<<256, 128, 0, stream>>>(Y2, bs2, xhat, V1, Vx);

    lin_t1_k<<<308, 256, 0, stream>>>(wg, bg, wh, bh, Vx, G, Hh, V1, wc1, t1);
    smsm_k<<<MM, 128, 0, stream>>>(Hh, G, A2);

    c1_k<<<132, 256, 0, stream>>>(A2, t1, bc1, c1, cnt);
    t2_k<<<88, 256, 0, stream>>>(c1, wc2, t2);
    v2f_k<<<MM, 256, 0, stream>>>(A2, t2, bc2, Xf2, V2m, cnt, (float*)d_out);
}

// Round 13
// 453.537 us; speedup vs baseline: 1.0373x; 1.0373x over previous
//
#include <hip/hip_runtime.h>
#include <hip/hip_bf16.h>
#include <math.h>

// ---------- dims ----------
#define BATCH 17
#define T_EX 16
#define H0 383
#define W0 287
#define C1 64
#define H1 95
#define W1 71
#define H1P 47
#define W1P 35
#define C2 192
#define H2P 23
#define W2P 17
#define C3 384
#define C45 256
#define H5P 11
#define W5P 8
#define DD 256
#define MM 88
#define TM 1408

#define HP1 389
#define WP1 292

typedef unsigned short ushort_t;
typedef __attribute__((ext_vector_type(8))) short short8;
typedef __attribute__((ext_vector_type(4))) float f32x4;

__device__ __forceinline__ float lrelu(float v) { return v > 0.f ? v : 0.01f * v; }

__device__ __forceinline__ ushort_t f2bf(float f) {
    unsigned int u = __float_as_uint(f);
    unsigned int r = (u + 0x7fffu + ((u >> 16) & 1u)) >> 16;
    return (ushort_t)r;
}
__device__ __forceinline__ float b2f(ushort_t b) {
    return __uint_as_float(((unsigned int)b) << 16);
}
__device__ __forceinline__ short8 ld16(const ushort_t* p) { return *(const short8*)p; }
__device__ __forceinline__ short8 ld2x8(const ushort_t* p) {
    union { uint2 u[2]; short8 s; } uu;
    uu.u[0] = *(const uint2*)p;
    uu.u[1] = *(const uint2*)(p + 4);
    return uu.s;
}
// async global -> LDS, 16B per lane; LDS dest = wave-uniform base + lane*16
__device__ __forceinline__ void async_cp16(ushort_t* l, const ushort_t* g) {
    __builtin_amdgcn_global_load_lds(
        (const __attribute__((address_space(1))) void*)g,
        (__attribute__((address_space(3))) void*)l, 16, 0, 0);
}

// ---------- conv weight prep body (shared by merged kernels) ----------
__device__ __forceinline__ void wprep_dev(const float* __restrict__ w,
                                          ushort_t* __restrict__ out,
                                          int KH, int KWl, int KWr, int CINl, int CINr,
                                          int NKS, int OCr, int idx) {
    int c = idx & 255;
    int rest = idx >> 8;
    int ks = rest % NKS;
    int ocb = rest / NKS;
    int k8 = c >> 6, m = c & 63;
    int oc = ocb * 64 + m;
    int KWC = KWl * CINl;
    ushort_t* o = out + (size_t)idx * 8;
#pragma unroll
    for (int j = 0; j < 8; ++j) {
        int kg = ks * 32 + k8 * 8 + j;
        int ky = kg / KWC; int rem = kg - ky * KWC;
        int kx = rem / CINl; int ic = rem - kx * CINl;
        float v = 0.f;
        if (oc < OCr && ky < KH && kx < KWr && ic < CINr)
            v = w[(((size_t)oc * CINr + ic) * KH + ky) * KWr + kx];
        o[j] = f2bf(v);
    }
}

// ---------- merged: conv1 input prep (pad-zero fused) + conv1 weight prep ----------
__global__ void prep1_wp1_k(const float* __restrict__ search, const float* __restrict__ exemp,
                            ushort_t* __restrict__ out, const float* __restrict__ w1,
                            ushort_t* __restrict__ WT) {
    const int pb = (BATCH * HP1 * WP1 + 255) / 256;   // 7543
    if ((int)blockIdx.x >= pb) {
        int idx = (blockIdx.x - pb) * 256 + threadIdx.x;
        if (idx < 4608) wprep_dev(w1, WT, 11, 12, 11, 4, 3, 18, 64, idx);
        return;
    }
    int idx = blockIdx.x * 256 + threadIdx.x;
    if (idx >= BATCH * HP1 * WP1) return;
    int x = idx % WP1; int t = idx / WP1;
    int y = t % HP1; int b = t / HP1;
    ushort4 o = {0, 0, 0, 0};
    int ix = x - 2, iy = y - 2;
    if (ix >= 0 && ix < W0 && iy >= 0 && iy < H0) {
        const float* src = (b == 0) ? search : exemp + (size_t)(b - 1) * 3 * H0 * W0;
        const int hw = H0 * W0;
        o.x = f2bf(src[iy * W0 + ix]);
        o.y = f2bf(src[hw + iy * W0 + ix]);
        o.z = f2bf(src[2 * hw + iy * W0 + ix]);
    }
    *(ushort4*)&out[(size_t)idx * 4] = o;
}

// ---------- merged: maxpool (pad-zero fused) + optional zfill + next conv wprep ----------
__global__ void pool_wp_k(const ushort_t* __restrict__ in, ushort_t* __restrict__ out,
                          int C, int Hin, int Win, int Hout, int Wout,
                          int OHp, int OWp, int OPAD,
                          float4* __restrict__ zp, int zn4,
                          const float* __restrict__ w, ushort_t* __restrict__ WT,
                          int KH, int KWl, int KWr, int CINl, int CINr,
                          int NKS, int nch, int OCr) {
    const int total = BATCH * C * OHp * OWp;
    const int pb = (total + 255) >> 8;
    const int zb = (zn4 + 255) >> 8;
    int bx = blockIdx.x;
    if (bx >= pb + zb) {
        int idx = (bx - pb - zb) * 256 + threadIdx.x;
        if (idx < nch) wprep_dev(w, WT, KH, KWl, KWr, CINl, CINr, NKS, OCr, idx);
        return;
    }
    if (bx >= pb) {
        int z = (bx - pb) * 256 + threadIdx.x;
        if (z < zn4) zp[z] = (float4){0.f, 0.f, 0.f, 0.f};
        return;
    }
    int idx = bx * 256 + threadIdx.x;
    if (idx >= total) return;
    int c = idx % C; int r = idx / C;
    int x = r % OWp; r /= OWp;
    int y = r % OHp; int b = r / OHp;
    int iy = y - OPAD, ix = x - OPAD;
    ushort_t v = 0;
    if (iy >= 0 && iy < Hout && ix >= 0 && ix < Wout) {
        const int rs = Win * C;
        const ushort_t* p = in + (((size_t)b * Hin + 2 * iy) * Win + 2 * ix) * C + c;
        float m = b2f(p[0]);
        m = fmaxf(m, b2f(p[C])); m = fmaxf(m, b2f(p[2 * C]));
        m = fmaxf(m, b2f(p[rs])); m = fmaxf(m, b2f(p[rs + C])); m = fmaxf(m, b2f(p[rs + 2 * C]));
        m = fmaxf(m, b2f(p[2 * rs])); m = fmaxf(m, b2f(p[2 * rs + C])); m = fmaxf(m, b2f(p[2 * rs + 2 * C]));
        v = f2bf(m);
    }
    out[idx] = v;
}

// ---------- merged: wprep4(WT2) + wprep5(WT3) + c4out zero-fill.
// Ordering audit: launches after conv3 (pool2 already consumed c2out=R1,
// conv3 already consumed WT) -> c4out zfill (R1[0..1.03M fl]) race-free;
// WT2/WT3 live at R1+2800640../3243008.. (beyond every live buffer at
// this point; PB overwrites WT2 only after conv4 consumed it). ----------
__global__ void wprep45_k(const float* __restrict__ aw4, ushort_t* __restrict__ WT2,
                          const float* __restrict__ aw5, ushort_t* __restrict__ WT3,
                          float4* __restrict__ zp) {
    int bx = blockIdx.x;
    if (bx < 432) {                 // wprep4 -> WT2 (110592 chunks)
        int idx = bx * 256 + threadIdx.x;
        if (idx < 110592) wprep_dev(aw4, WT2, 3, 3, 3, 384, 384, 108, 256, idx);
    } else if (bx < 720) {          // wprep5 -> WT3 (73728 chunks)
        int idx = (bx - 432) * 256 + threadIdx.x;
        if (idx < 73728) wprep_dev(aw5, WT3, 3, 3, 3, 256, 256, 72, 256, idx);
    } else {                        // c4out zero-fill (258400 float4)
        int z = (bx - 720) * 256 + threadIdx.x;
        if (z < 258400) zp[z] = (float4){0.f, 0.f, 0.f, 0.f};
    }
}

// ====================================================================
// bf16 MFMA implicit-GEMM conv, v14 (41us conv2, r8/r11-verified):
//  2x2 wave grid (32oc x 32px per wave), batch-flattened N,
//  A via global_load_lds DMA, B px-major coalesced reg-staged with
//  conflict-free XOR swizzle (r7-verified, SQ_LDS_BANK_CONFLICT==0).
// ====================================================================
template <int STRIDE, bool A16>
__global__ __launch_bounds__(256) void conv_mfma14(
    const ushort_t* __restrict__ inp, const ushort_t* __restrict__ wt,
    const float* __restrict__ bias, ushort_t* __restrict__ out,
    int Hp, int Wp, int C, int Wout, int HW, int Ntot, int NKS2, int KWl,
    int OHp, int OWp, int OPAD, int COUT) {
    const int tid = threadIdx.x;
    const int wv = tid >> 6, lane = tid & 63;
    const int quad = lane >> 4, l16 = lane & 15;
    const int wr = wv >> 1, wc = wv & 1;
    const int n_blk = blockIdx.x * 64;
    const int ocb = blockIdx.y;

    __shared__ ushort_t As[2][4096];
    __shared__ ushort_t Bs[2][4096];
    __shared__ int offs[432];

    const int KWC = KWl * C;
    for (int g = tid; g < NKS2 * 8; g += 256) {
        int kg = g * 8;
        int ky = kg / KWC; int rem = kg - ky * KWC;
        int kx = rem / C; int c8 = rem - kx * C;
        offs[g] = (ky * Wp + kx) * C + c8;
    }

    const size_t HWC = (size_t)Hp * Wp * C;
    const int g8 = lane & 7, po = lane >> 3;
    const ushort_t* bsrc0 = nullptr; const ushort_t* bsrc1 = nullptr;
    const ushort_t* lsrc = nullptr;
    int ws0 = 0, ws1 = 0;
    if constexpr (A16) {
        int np0 = n_blk + wv * 16 + po;      if (np0 >= Ntot) np0 = Ntot - 1;
        int np1 = n_blk + wv * 16 + 8 + po;  if (np1 >= Ntot) np1 = Ntot - 1;
        int b0 = np0 / HW, p0 = np0 - b0 * HW;
        int b1 = np1 / HW, p1 = np1 - b1 * HW;
        int oy0 = p0 / Wout, ox0 = p0 - oy0 * Wout;
        int oy1 = p1 / Wout, ox1 = p1 - oy1 * Wout;
        bsrc0 = inp + (size_t)b0 * HWC + (size_t)(oy0 * STRIDE * Wp + ox0 * STRIDE) * C;
        bsrc1 = inp + (size_t)b1 * HWC + (size_t)(oy1 * STRIDE * Wp + ox1 * STRIDE) * C;
        ws0 = g8 * 512 + (((wv * 16 + po) ^ g8) * 8);
        ws1 = g8 * 512 + (((wv * 16 + 8 + po) ^ g8) * 8);
    } else {
        int n0 = n_blk + lane; if (n0 >= Ntot) n0 = Ntot - 1;
        int b0 = n0 / HW, p0 = n0 - b0 * HW;
        int oy = p0 / Wout, ox = p0 - oy * Wout;
        lsrc = inp + (size_t)b0 * HWC + (size_t)(oy * STRIDE * Wp + ox * STRIDE) * C;
    }

    f32x4 acc[2][2];
#pragma unroll
    for (int am = 0; am < 2; ++am)
#pragma unroll
        for (int bn = 0; bn < 2; ++bn) acc[am][bn] = (f32x4){0.f, 0.f, 0.f, 0.f};

    const ushort_t* wblk = wt + (size_t)ocb * (size_t)NKS2 * 4096;

    __syncthreads();   // offs ready

    {
        const ushort_t* aS = wblk + tid * 8;
        async_cp16(&As[0][tid * 8], aS);
        async_cp16(&As[0][2048 + tid * 8], aS + 2048);
        if constexpr (A16) {
            *(short8*)&Bs[0][ws0] = ld16(bsrc0 + offs[g8]);
            *(short8*)&Bs[0][ws1] = ld16(bsrc1 + offs[g8]);
        } else {
            const int o0 = offs[wv], o1 = offs[4 + wv];
            *(short8*)&Bs[0][tid * 8] = ld2x8(lsrc + o0);
            *(short8*)&Bs[0][2048 + tid * 8] = ld2x8(lsrc + o1);
        }
    }
    __syncthreads();

    for (int ks2 = 0; ks2 < NKS2; ++ks2) {
        const int cur = ks2 & 1, nxt = cur ^ 1;
        const bool more = (ks2 + 1 < NKS2);
        short8 rb0, rb1;
        if (more) {
            const ushort_t* aS = wblk + (size_t)(ks2 + 1) * 4096 + tid * 8;
            async_cp16(&As[nxt][tid * 8], aS);
            async_cp16(&As[nxt][2048 + tid * 8], aS + 2048);
            if constexpr (A16) {
                rb0 = ld16(bsrc0 + offs[(ks2 + 1) * 8 + g8]);
                rb1 = ld16(bsrc1 + offs[(ks2 + 1) * 8 + g8]);
            } else {
                const int o0 = offs[(ks2 + 1) * 8 + wv], o1 = offs[(ks2 + 1) * 8 + 4 + wv];
                *(short8*)&Bs[nxt][tid * 8] = ld2x8(lsrc + o0);
                *(short8*)&Bs[nxt][2048 + tid * 8] = ld2x8(lsrc + o1);
            }
        }
#pragma unroll
        for (int h = 0; h < 2; ++h) {
            const short8 a0 = *(const short8*)&As[cur][h * 2048 + (quad * 64 + wr * 32 + l16) * 8];
            const short8 a1 = *(const short8*)&As[cur][h * 2048 + (quad * 64 + wr * 32 + 16 + l16) * 8];
            short8 b0, b1;
            if constexpr (A16) {
                b0 = *(const short8*)&Bs[cur][h * 2048 + quad * 512 + (((wc * 32 + l16) ^ (h * 4 + quad)) * 8)];
                b1 = *(const short8*)&Bs[cur][h * 2048 + quad * 512 + (((wc * 32 + 16 + l16) ^ (h * 4 + quad)) * 8)];
            } else {
                b0 = *(const short8*)&Bs[cur][h * 2048 + (quad * 64 + wc * 32 + l16) * 8];
                b1 = *(const short8*)&Bs[cur][h * 2048 + (quad * 64 + wc * 32 + 16 + l16) * 8];
            }
            acc[0][0] = __builtin_amdgcn_mfma_f32_16x16x32_bf16(a0, b0, acc[0][0], 0, 0, 0);
            acc[0][1] = __builtin_amdgcn_mfma_f32_16x16x32_bf16(a0, b1, acc[0][1], 0, 0, 0);
            acc[1][0] = __builtin_amdgcn_mfma_f32_16x16x32_bf16(a1, b0, acc[1][0], 0, 0, 0);
            acc[1][1] = __builtin_amdgcn_mfma_f32_16x16x32_bf16(a1, b1, acc[1][1], 0, 0, 0);
        }
        if constexpr (A16) {
            if (more) {
                *(short8*)&Bs[nxt][ws0] = rb0;
                *(short8*)&Bs[nxt][ws1] = rb1;
            }
        }
        __syncthreads();
    }

    const int oc0 = ocb * 64 + wr * 32 + quad * 4;
#pragma unroll
    for (int bn = 0; bn < 2; ++bn) {
        int n = n_blk + wc * 32 + bn * 16 + l16;
        if (n < Ntot) {
            int bb = n / HW; int pix = n - bb * HW;
            int y = pix / Wout, x = pix - y * Wout;
            size_t base = (((size_t)bb * OHp + y + OPAD) * OWp + x + OPAD) * COUT;
#pragma unroll
            for (int am = 0; am < 2; ++am) {
                const int oc = oc0 + am * 16;
                ushort4 o;
                o.x = f2bf(fmaxf(acc[am][bn][0] + bias[oc], 0.f));
                o.y = f2bf(fmaxf(acc[am][bn][1] + bias[oc + 1], 0.f));
                o.z = f2bf(fmaxf(acc[am][bn][2] + bias[oc + 2], 0.f));
                o.w = f2bf(fmaxf(acc[am][bn][3] + bias[oc + 3], 0.f));
                *(ushort4*)&out[base + oc] = o;
            }
        }
    }
}

// ====================================================================
// Generic bf16 MFMA GEMM body (device fn).
// ====================================================================
template <int MODE, bool HASBIAS, bool SC1>
__device__ __forceinline__ void gemm_dev(
    ushort_t (*Bs)[2048],
    const ushort_t* __restrict__ Bsrc, const ushort_t* __restrict__ wt,
    const float* __restrict__ bias, float* __restrict__ out,
    int RS, int N, int NKS, int sn, int sc, int bx, int by) {
    const int tid = threadIdx.x;
    const int wv = tid >> 6, lane = tid & 63;
    const int quad = lane >> 4, l16 = lane & 15;
    const int n_blk = bx * 64;
    const int ocb = by;

    int n_g = n_blk + lane;
    int n_gc = n_g < N ? n_g : N - 1;
    int row = (MODE == 1) ? (1 + (n_gc & 15)) * MM + (n_gc >> 4) : n_gc;
    const size_t base0 = (size_t)row * RS;

    f32x4 acc[4];
#pragma unroll
    for (int cn = 0; cn < 4; ++cn) acc[cn] = (f32x4){0.f, 0.f, 0.f, 0.f};

    const ushort_t* wblk = wt + (size_t)ocb * NKS * 2048;
    const int afrag = (quad * 64 + wv * 16 + l16) * 8;

    short8 a0 = ld16(wblk + afrag);
    *(short8*)&Bs[0][tid * 8] = ld16(Bsrc + base0 + wv * 8);
    __syncthreads();

    for (int ks = 0; ks < NKS; ++ks) {
        const int cur = ks & 1, nxt = cur ^ 1;
        short8 a1, bn;
        const bool more = (ks + 1 < NKS);
        if (more) {
            a1 = ld16(wblk + (ks + 1) * 2048 + afrag);
            bn = ld16(Bsrc + base0 + (ks + 1) * 32 + wv * 8);
        }
#pragma unroll
        for (int cn = 0; cn < 4; ++cn) {
            const short8 bfr = *(const short8*)&Bs[cur][(quad * 64 + cn * 16 + l16) * 8];
            acc[cn] = __builtin_amdgcn_mfma_f32_16x16x32_bf16(a0, bfr, acc[cn], 0, 0, 0);
        }
        if (more) *(short8*)&Bs[nxt][tid * 8] = bn;
        a0 = a1;
        __syncthreads();
    }

    const int oc0 = ocb * 64 + wv * 16 + quad * 4;
    float bb[4] = {0.f, 0.f, 0.f, 0.f};
    if (HASBIAS) { bb[0] = bias[oc0]; bb[1] = bias[oc0+1]; bb[2] = bias[oc0+2]; bb[3] = bias[oc0+3]; }
#pragma unroll
    for (int cn = 0; cn < 4; ++cn) {
        int n = n_blk + cn * 16 + l16;
        if (n < N) {
            if (SC1) {
                float4 o;
                o.x = acc[cn][0] + bb[0]; o.y = acc[cn][1] + bb[1];
                o.z = acc[cn][2] + bb[2]; o.w = acc[cn][3] + bb[3];
                *(float4*)&out[(size_t)n * sn + oc0] = o;
            } else {
#pragma unroll
                for (int reg = 0; reg < 4; ++reg)
                    out[(size_t)n * sn + (size_t)(oc0 + reg) * sc] = acc[cn][reg] + bb[reg];
            }
        }
    }
}

template <int MODE, bool HASBIAS, bool SC1>
__global__ __launch_bounds__(256) void gemm_mfma3_k(
    const ushort_t* __restrict__ Bsrc, const ushort_t* __restrict__ wt,
    const float* __restrict__ bias, float* __restrict__ out,
    int RS, int N, int NKS, int sn, int sc) {
    __shared__ ushort_t Bs[2][2048];
    gemm_dev<MODE, HASBIAS, SC1>(Bs, Bsrc, wt, bias, out, RS, N, NKS, sn, sc,
                                 blockIdx.x, blockIdx.y);
}

// merged launch: xc-gemm (2x4 blocks) + Y1-gemm (22x8 blocks); grid (24,8)
__global__ __launch_bounds__(256) void gemm_pair_k(
    const ushort_t* __restrict__ XfPad, const ushort_t* __restrict__ WCDT,
    const float* __restrict__ bcd, float* __restrict__ xc,
    const ushort_t* __restrict__ PB, const ushort_t* __restrict__ WS1T,
    float* __restrict__ Y1) {
    __shared__ ushort_t Bs[2][2048];
    if (blockIdx.x < 2) {
        if (blockIdx.y < 4)
            gemm_dev<0, true, false>(Bs, XfPad, WCDT, bcd, xc, 256, MM, 24, 1, MM,
                                     blockIdx.x, blockIdx.y);
    } else {
        gemm_dev<1, false, true>(Bs, PB, WS1T, nullptr, Y1, 256, TM, 8, 512, 1,
                                 blockIdx.x - 2, blockIdx.y);
    }
}

// ---------- merged: gemm weight prep (ws1|ws2|wcd) + pool5 ----------
__global__ void wg_pool5_k(const float* __restrict__ ws1, const float* __restrict__ ws2,
                           const float* __restrict__ wcd, ushort_t* __restrict__ WS1T,
                           ushort_t* __restrict__ WS2T, ushort_t* __restrict__ WCDT,
                           const ushort_t* __restrict__ in, float* __restrict__ P,
                           ushort_t* __restrict__ PB, ushort_t* __restrict__ XfPad) {
    if (blockIdx.x < 224) {
        int idx = blockIdx.x * 256 + threadIdx.x;
        const float* src; ushort_t* dst; int NKS, mode = 0, sa = 1, sk = 0, base;
        if (idx < 16384)       { src = ws1; dst = WS1T; NKS = 8;  sk = 512; base = idx; }
        else if (idx < 32768)  { src = ws2; dst = WS2T; NKS = 16; sk = 256; base = idx - 16384; }
        else                   { src = wcd; dst = WCDT; NKS = 24; mode = 1; base = idx - 32768; }
        int c = base & 255;
        int rest = base >> 8;
        int ks = rest % NKS;
        int ocb = rest / NKS;
        int k8 = c >> 6, m = c & 63;
        int oc = ocb * 64 + m;
        ushort_t* o = dst + (size_t)base * 8;
#pragma unroll
        for (int j = 0; j < 8; ++j) {
            int kg = ks * 32 + k8 * 8 + j;
            float v;
            if (mode == 0) v = src[(size_t)oc * sa + (size_t)kg * sk];
            else           v = src[(size_t)oc * 768 + (kg & 255) * 3 + (kg >> 8)];
            o[j] = f2bf(v);
        }
    } else {
        int idx = (blockIdx.x - 224) * 256 + threadIdx.x;
        if (idx >= BATCH * 256 * MM) return;
        int c = idx % 256; int r = idx / 256;
        int x = r % W5P; r /= W5P;
        int y = r % H5P; int b = r / H5P;
        const int rs = W2P * 256;
        const ushort_t* p = in + (((size_t)b * H2P + 2 * y) * W2P + 2 * x) * 256 + c;
        float m = b2f(p[0]);
        m = fmaxf(m, b2f(p[256])); m = fmaxf(m, b2f(p[512]));
        m = fmaxf(m, b2f(p[rs])); m = fmaxf(m, b2f(p[rs + 256])); m = fmaxf(m, b2f(p[rs + 512]));
        m = fmaxf(m, b2f(p[2 * rs])); m = fmaxf(m, b2f(p[2 * rs + 256])); m = fmaxf(m, b2f(p[2 * rs + 512]));
        int mm = y * W5P + x;
        size_t o = ((size_t)b * MM + mm) * 256 + c;
        P[o] = m;
        ushort_t mb = f2bf(m);
        PB[o] = mb;
        if (b == 0) XfPad[(size_t)(mm + 1) * 256 + c] = mb;
    }
}

// ---------- merged: xhat (with in-block vmax) + sh1 (r8 config, 120x256) ----------
__global__ void xhat_sh1_k(const float* __restrict__ xc, const float* __restrict__ wt,
                           const float* __restrict__ bt, float* __restrict__ xhat,
                           const float* __restrict__ Y1, const float* __restrict__ bs1,
                           ushort_t* __restrict__ h1b) {
    if (blockIdx.x < 88) {
        __shared__ float lv[256];
        {
            int j = threadIdx.x;
            const float* xr = xc + (size_t)j * MM;
            float mx = xr[0];
            for (int k = 1; k < MM; ++k) mx = fmaxf(mx, xr[k]);
            lv[j] = mx;
        }
        __syncthreads();
        int idx = blockIdx.x * 256 + threadIdx.x;
        if (idx >= DD * MM) return;
        int k = idx % MM, o = idx / MM;
        float acc = bt[o];
        for (int i = 0; i < 256; ++i) acc = fmaf(lv[i], wt[(i * 256 + o) * MM + k], acc);
        xhat[idx] = acc;
    } else {
        int idx = (blockIdx.x - 88) * 256 + threadIdx.x;
        if (idx >= T_EX * 512) return;
        int c = idx & 511, t = idx >> 9;
        float s = 0.f;
        for (int m = 0; m < MM; ++m) s += Y1[(size_t)(m * T_EX + t) * 512 + c];
        float base = s + bs1[c];
        if (t == 0) {
            for (int m = 0; m < MM; ++m) {
                float val = base - Y1[(size_t)(m * T_EX) * 512 + c];
                h1b[(size_t)(m * T_EX) * 512 + c] = f2bf(lrelu(val));
            }
        } else {
            ushort_t v = f2bf(lrelu(base));
            for (int m = 0; m < MM; ++m)
                h1b[(size_t)(m * T_EX + t) * 512 + c] = v;
        }
    }
}

// ---------- fused sh2 + v1vx (r9/r11-verified bit-exact) ----------
__global__ void sh2v1_k(const float* __restrict__ Y2, const float* __restrict__ bs2,
                        const float* __restrict__ xhat,
                        float* __restrict__ V1, float* __restrict__ Vx) {
    int d = blockIdx.x;
    int tid = threadIdx.x;   // 128
    __shared__ float S2s[16];
    if (tid < 16) {
        float s = 0.f;
        for (int m = 0; m < MM; ++m) s += Y2[(size_t)(m * T_EX + tid) * 256 + d];
        S2s[tid] = s + bs2[d];
    }
    __syncthreads();
    for (int m = tid; m < MM; m += 128) {
        float y0 = Y2[(size_t)(m * T_EX) * 256 + d];
        float mx = -INFINITY;
        for (int t = 0; t < T_EX; ++t) {
            float val = (t == 0) ? lrelu(S2s[0] - y0) : lrelu(S2s[t]);
            mx = fmaxf(mx, val);
        }
        int idx = d * MM + m;
        V1[idx] = mx;
        Vx[idx] = mx + xhat[idx];
    }
}

// ---------- merged: lin88 (g & h) + t1 (r8 config, 308x256) ----------
__global__ void lin_t1_k(const float* __restrict__ Wgm, const float* __restrict__ bg,
                         const float* __restrict__ Whm, const float* __restrict__ bh,
                         const float* __restrict__ Vx, float* __restrict__ G,
                         float* __restrict__ Hh,
                         const float* __restrict__ V1, const float* __restrict__ wc1,
                         float* __restrict__ t1) {
    int bx = blockIdx.x;
    if (bx < 176) {
        int sel = bx >= 88;
        int idx = (bx - (sel ? 88 : 0)) * 256 + threadIdx.x;
        if (idx >= DD * MM) return;
        const float* W = sel ? Whm : Wgm;
        const float* bias = sel ? bh : bg;
        float* out = sel ? Hh : G;
        int m = idx % MM, o = idx / MM;
        const float* wr = W + o * 256;
        float acc = bias[o];
        for (int i = 0; i < 256; ++i) acc = fmaf(wr[i], Vx[i * MM + m], acc);
        out[idx] = acc;
    } else {
        int idx = (bx - 176) * 256 + threadIdx.x;
        if (idx >= MM * 384) return;
        int c = idx % 384, m = idx / 384;
        float acc = 0.f;
        for (int d = 0; d < 256; ++d) acc = fmaf(V1[d * MM + m], wc1[d * 384 + c], acc);
        t1[idx] = acc;
    }
}

// ---------- fused Smat row + softmax ----------
__global__ void smsm_k(const float* __restrict__ Hh, const float* __restrict__ G,
                       float* __restrict__ A2) {
    int j = blockIdx.x;
    int tid = threadIdx.x;   // 128
    __shared__ float row[96];
    __shared__ float red[128];
    for (int i = tid; i < MM; i += 128) {
        float acc = 0.f;
        for (int c = 0; c < 256; ++c) acc = fmaf(Hh[c * MM + j], G[c * MM + i], acc);
        row[i] = acc;
    }
    __syncthreads();
    float val = (tid < MM) ? row[tid] : -INFINITY;
    red[tid] = val; __syncthreads();
    for (int s = 64; s > 0; s >>= 1) {
        if (tid < s) red[tid] = fmaxf(red[tid], red[tid + s]);
        __syncthreads();
    }
    float mx = red[0]; __syncthreads();
    float e = (tid < MM) ? expf(val - mx) : 0.f;
    red[tid] = e; __syncthreads();
    for (int s = 64; s > 0; s >>= 1) {
        if (tid < s) red[tid] += red[tid + s];
        __syncthreads();
    }
    float inv = 1.f / red[0];
    if (tid < MM) A2[j * MM + tid] = e * inv;
}

// ---------- c1 (132x256); block 0 zeroes the v2f counter ----------
__global__ void c1_k(const float* __restrict__ A2, const float* __restrict__ t1,
                     const float* __restrict__ bc1, float* __restrict__ c1,
                     unsigned* __restrict__ cnt) {
    if (blockIdx.x == 0 && threadIdx.x == 0) *cnt = 0u;
    int idx = blockIdx.x * 256 + threadIdx.x;
    if (idx >= MM * 384) return;
    int c = idx % 384, j = idx / 384;
    float acc = bc1[c];
    for (int i = 0; i < MM; ++i) acc = fmaf(A2[j * MM + i], t1[i * 384 + c], acc);
    c1[idx] = lrelu(acc);
}

// ---------- t2 (88x256) ----------
__global__ void t2_k(const float* __restrict__ c1, const float* __restrict__ wc2,
                     float* __restrict__ t2) {
    int idx = blockIdx.x * 256 + threadIdx.x;
    if (idx >= MM * 256) return;
    int c = idx % 256, m = idx / 256;
    const float* cr = c1 + m * 384;
    float acc = 0.f;
    for (int d = 0; d < 384; ++d) acc = fmaf(cr[d], wc2[d * 256 + c], acc);
    t2[idx] = acc;
}

// ---------- fused v2 + final (r9/r11-verified deterministic last-block) ----------
__global__ __launch_bounds__(256) void v2f_k(const float* __restrict__ A2,
                                             const float* __restrict__ t2,
                                             const float* __restrict__ bc2,
                                             const float* __restrict__ Xf2,
                                             float* __restrict__ V2m,
                                             unsigned* __restrict__ cnt,
                                             float* __restrict__ out) {
    int j = blockIdx.x;   // 88
    int tid = threadIdx.x;
    __shared__ float a2row[88];
    if (tid < 88) a2row[tid] = A2[j * MM + tid];
    __syncthreads();
    {
        int c = tid;
        float acc = bc2[c];
        for (int i = 0; i < MM; ++i) acc = fmaf(a2row[i], t2[i * 256 + c], acc);
        V2m[(size_t)j * 256 + c] = lrelu(acc);
    }
    __threadfence();
    __syncthreads();
    __shared__ bool last;
    if (tid == 0) last = (atomicAdd(cnt, 1u) == 87u);
    __syncthreads();
    if (last) {
        __threadfence();
        __shared__ float red[256];
        float acc = 0.f;
        for (int idx = tid; idx < DD * MM; idx += 256)
            acc = fmaf(Xf2[idx], V2m[idx], acc);
        red[tid] = acc; __syncthreads();
        for (int s = 128; s > 0; s >>= 1) {
            if (tid < s) red[tid] += red[tid + s];
            __syncthreads();
        }
        if (tid == 0) out[0] = red[0];
    }
}

extern "C" void kernel_launch(void* const* d_in, const int* in_sizes, int n_in,
                              void* d_out, int out_size, void* d_ws, size_t ws_size,
                              hipStream_t stream) {
    const float* search = (const float*)d_in[0];
    const float* exemp  = (const float*)d_in[1];
    const float* aw1 = (const float*)d_in[2];  const float* ab1 = (const float*)d_in[3];
    const float* aw2 = (const float*)d_in[4];  const float* ab2 = (const float*)d_in[5];
    const float* aw3 = (const float*)d_in[6];  const float* ab3 = (const float*)d_in[7];
    const float* aw4 = (const float*)d_in[8];  const float* ab4 = (const float*)d_in[9];
    const float* aw5 = (const float*)d_in[10]; const float* ab5 = (const float*)d_in[11];
    const float* wcd = (const float*)d_in[12]; const float* bcd = (const float*)d_in[13];
    const float* wt  = (const float*)d_in[14]; const float* bt  = (const float*)d_in[15];
    const float* ws1 = (const float*)d_in[16]; const float* bs1 = (const float*)d_in[17];
    const float* ws2 = (const float*)d_in[18]; const float* bs2 = (const float*)d_in[19];
    const float* wg  = (const float*)d_in[20]; const float* bg  = (const float*)d_in[21];
    const float* wh  = (const float*)d_in[22]; const float* bh  = (const float*)d_in[23];
    const float* wc1 = (const float*)d_in[24]; const float* bc1 = (const float*)d_in[25];
    const float* wc2 = (const float*)d_in[26]; const float* bc2 = (const float*)d_in[27];

    float* ws = (float*)d_ws;
    float* R1 = ws;
    float* R2 = ws + 3870720;
    float* R3 = ws + 7544832;
    float* Wg = ws + 8628864;

    ushort_t* in1p  = (ushort_t*)R1;
    ushort_t* c1out = (ushort_t*)R2;
    ushort_t* p1out = (ushort_t*)R3;
    ushort_t* c2out = (ushort_t*)R1;
    ushort_t* p2out = (ushort_t*)R2;
    ushort_t* c3out = (ushort_t*)(R2 + 775200);
    ushort_t* c4out = (ushort_t*)R1;
    ushort_t* c5out = (ushort_t*)R3;
    ushort_t* WT    = (ushort_t*)Wg;                  // conv1/2/3 (sequential reuse)
    ushort_t* WT2   = (ushort_t*)(R1 + 2800640);      // conv4 weights (audited-dead space)
    ushort_t* WT3   = (ushort_t*)(R1 + 3243008);      // conv5 weights

    // ---- conv stack (r11-proven config; one extra launch merge: wprep4+5) ----
    prep1_wp1_k<<<7543 + 18, 256, 0, stream>>>(search, exemp, in1p, aw1, WT);
    conv_mfma14<4, false><<<dim3(1792, 1), 256, 0, stream>>>(
        in1p, WT, ab1, c1out, HP1, WP1, 4, W1, H1 * W1, BATCH * H1 * W1, 9, 12, H1, W1, 0, 64);
    pool_wp_k<<<8454 + 150, 256, 0, stream>>>(
        c1out, p1out, 64, H1, W1, H1P, W1P, 51, 39, 2, nullptr, 0,
        aw2, WT, 5, 5, 5, 64, 64, 50, 38400, 192);
    conv_mfma14<1, true><<<dim3(437, 3), 256, 0, stream>>>(
        p1out, WT, ab2, c2out, 51, 39, 64, W1P, H1P * W1P, BATCH * H1P * W1P, 25, 5, H1P, W1P, 0, 192);
    pool_wp_k<<<6057 + 1515 + 324, 256, 0, stream>>>(
        c2out, p2out, 192, H1P, W1P, H2P, W2P, 25, 19, 1,
        (float4*)(R2 + 775200), 387600,
        aw3, WT, 3, 3, 3, 192, 192, 54, 82944, 384);
    conv_mfma14<1, true><<<dim3(104, 6), 256, 0, stream>>>(
        p2out, WT, ab3, c3out, 25, 19, 192, W2P, H2P * W2P, BATCH * H2P * W2P, 27, 3, 25, 19, 1, 384);
    // merged: wprep4(WT2) + wprep5(WT3) + c4out zero-fill (1730 blocks)
    wprep45_k<<<1730, 256, 0, stream>>>(aw4, WT2, aw5, WT3, (float4*)R1);
    conv_mfma14<1, true><<<dim3(104, 4), 256, 0, stream>>>(
        c3out, WT2, ab4, c4out, 25, 19, 384, W2P, H2P * W2P, BATCH * H2P * W2P, 54, 3, 25, 19, 1, 256);
    conv_mfma14<1, true><<<dim3(104, 4), 256, 0, stream>>>(
        c4out, WT3, ab5, c5out, 25, 19, 256, W2P, H2P * W2P, BATCH * H2P * W2P, 36, 3, H2P, W2P, 0, 256);

    // ---- tail region layout in R1 ----
    float*    P      = R1 + 2417664;
    ushort_t* PB     = (ushort_t*)(R1 + 2800640);
    ushort_t* XfPad  = (ushort_t*)(R1 + 2992128);
    float*    xc     = R1 + 3003648;

    ushort_t* WS1T = (ushort_t*)Wg;
    ushort_t* WS2T = (ushort_t*)(Wg + 65536);
    ushort_t* WCDT = (ushort_t*)(Wg + 131072);

    wg_pool5_k<<<224 + (BATCH * 256 * MM + 255) / 256, 256, 0, stream>>>(
        ws1, ws2, wcd, WS1T, WS2T, WCDT, c5out, P, PB, XfPad);
    float* Xf2 = P;

    float* xhat = R1 + 1024;
    float* Y1   = R1 + 23552;
    ushort_t* h1b = (ushort_t*)(R1 + 752640);
    float* Y2   = R1 + 1473536;
    float* V1   = R1 + 2198528;
    float* Vx   = R1 + 2221056;
    float* G    = R1 + 2243584;
    float* Hh   = R1 + 2266112;
    float* A2   = R1 + 2296832;
    float* t1   = R1 + 2305024;
    float* c1   = R1 + 2338816;
    float* t2   = R1 + 2372608;
    float* V2m  = R1 + 2395136;
    unsigned* cnt = (unsigned*)(R1 + 512);   // scratch; zeroed by c1_k

    gemm_pair_k<<<dim3(24, 8), 256, 0, stream>>>(XfPad, WCDT, bcd, xc, PB, WS1T, Y1);
    xhat_sh1_k<<<120, 256, 0, stream>>>(xc, wt, bt, xhat, Y1, bs1, h1b);

    gemm_mfma3_k<0, false, true><<<dim3(22, 4), 256, 0, stream>>>(
        h1b, WS2T, nullptr, Y2, 512, TM, 16, 256, 1);
    sh2v1_k<<<256, 128, 0, stream>>>(Y2, bs2, xhat, V1, Vx);

    lin_t1_k<<<308, 256, 0, stream>>>(wg, bg, wh, bh, Vx, G, Hh, V1, wc1, t1);
    smsm_k<<<MM, 128, 0, stream>>>(Hh, G, A2);

    c1_k<<<132, 256, 0, stream>>>(A2, t1, bc1, c1, cnt);
    t2_k<<<88, 256, 0, stream>>>(c1, wc2, t2);
    v2f_k<<<MM, 256, 0, stream>>>(A2, t2, bc2, Xf2, V2m, cnt, (float*)d_out);
}